// Round 1
// baseline (498.003 us; speedup 1.0000x reference)
//
#include <hip/hip_runtime.h>

#define D 128
#define BG 8192
#define NPG 64
#define NNODES (BG * NPG)
#define NL 14

typedef __attribute__((ext_vector_type(8))) __bf16 bf16x8;
typedef __attribute__((ext_vector_type(16))) float f32x16;

__device__ __forceinline__ unsigned short f2bf(float f) {
  unsigned int u = __float_as_uint(f);
  u += 0x7fffu + ((u >> 16) & 1u);
  return (unsigned short)(u >> 16);
}

// ---------------- kernel 1: cbias (per-graph partner bias) + W-mid bf16 prep ----------------
// blocks 0..255: cbias for 32 graphs each.  block 256: convert Wp1[128:256] to
// pre-swizzled bf16 (layout: u16 idx = col*128 + (k ^ ((col&15)<<3)) — matches
// the partner kernel's LDS fragment reads).
__global__ __launch_bounds__(256) void k_prep(
    const float* __restrict__ node, const float* __restrict__ glob,
    const float* __restrict__ Wp1, const float* __restrict__ bp1,
    float* __restrict__ ws_cb, unsigned short* __restrict__ ws_wmid)
{
  const int tid = threadIdx.x;
  const int blk = blockIdx.x;
  if (blk == 256) {
    #pragma unroll
    for (int i = 0; i < 64; ++i) {
      int flat = tid + i * 256;          // 16384 elements
      int k = flat >> 7, col = flat & 127;
      ws_wmid[col * 128 + (k ^ ((col & 15) << 3))] =
          f2bf(Wp1[(size_t)(128 + k) * D + col]);
    }
    return;
  }
  __shared__ float in_s[32][256];        // [graph][cur(128) | glob(128)]
  const int g0 = blk * 32;
  #pragma unroll
  for (int i = 0; i < 8; ++i) {
    int idx = tid + i * 256;             // float4 index, 2048 total
    int r = idx >> 6, c4 = idx & 63;
    int g = g0 + r;
    float4 v;
    if (c4 < 32) v = ((const float4*)(node + (size_t)((g + 1) * NPG - 1) * D))[c4];
    else         v = ((const float4*)(glob + (size_t)g * D))[c4 - 32];
    *(float4*)&in_s[r][c4 * 4] = v;
  }
  __syncthreads();
  const int lane = tid & 31, grp = tid >> 5;   // 8 groups x 4 graphs
  float acc[4][4] = {};
  for (int k4 = 0; k4 < 64; ++k4) {
    int k = k4 * 4;
    float wv[4][4];
    #pragma unroll
    for (int kk = 0; kk < 4; ++kk) {
      int krow = k + kk;
      int wr = krow < 128 ? krow : krow + 128;   // skip node-block of Wp1
      const float* wp = Wp1 + (size_t)wr * D + lane;
      #pragma unroll
      for (int m = 0; m < 4; ++m) wv[kk][m] = wp[32 * m];
    }
    #pragma unroll
    for (int g = 0; g < 4; ++g) {
      float4 iv = *(const float4*)&in_s[grp * 4 + g][k];
      float ie[4] = {iv.x, iv.y, iv.z, iv.w};
      #pragma unroll
      for (int kk = 0; kk < 4; ++kk)
        #pragma unroll
        for (int m = 0; m < 4; ++m) acc[g][m] += ie[kk] * wv[kk][m];
    }
  }
  #pragma unroll
  for (int g = 0; g < 4; ++g)
    #pragma unroll
    for (int m = 0; m < 4; ++m) {
      int j = lane + 32 * m;
      ws_cb[(size_t)(g0 + grp * 4 + g) * D + j] = acc[g][m] + bp1[j];
    }
}

// ---------------- kernel 2: partner logits (MFMA bf16 GEMM + fused epilogue) ----------------
// block = 256 thr (4 waves), 128 node rows x 128 cols, K=128.
__global__ __launch_bounds__(256) void k_partner(
    const float* __restrict__ node,
    const unsigned short* __restrict__ wmid,   // pre-swizzled bf16 W
    const float* __restrict__ ws_cb,
    const float* __restrict__ Wp2, const float* __restrict__ bp2,
    float* __restrict__ out)
{
  __shared__ unsigned short lds_a[128 * 128];  // 32 KB, swizzled bf16 A
  __shared__ unsigned short lds_w[128 * 128];  // 32 KB, swizzled bf16 W
  const int tid = threadIdx.x;
  const int blk = blockIdx.x;
  const size_t row0 = (size_t)blk * 128;

  // stage A: 128 rows x 128 f32 -> bf16, byte ^= (row&15)<<4 swizzle
  const float4* A4 = (const float4*)(node + row0 * D);
  #pragma unroll
  for (int i = 0; i < 16; ++i) {
    int idx = tid + i * 256;                   // 4096 float4
    int r = idx >> 5, c4 = idx & 31;
    float4 v = A4[idx];
    unsigned int lo = (unsigned)f2bf(v.x) | ((unsigned)f2bf(v.y) << 16);
    unsigned int hi = (unsigned)f2bf(v.z) | ((unsigned)f2bf(v.w) << 16);
    uint2 pk = make_uint2(lo, hi);
    int byteoff = (c4 * 8) ^ ((r & 15) << 4);
    *(uint2*)((char*)lds_a + r * 256 + byteoff) = pk;
  }
  // stage W: flat 32 KB copy (already swizzled in ws)
  const uint4* Wsrc = (const uint4*)wmid;
  uint4* Wdst = (uint4*)lds_w;
  #pragma unroll
  for (int i = 0; i < 8; ++i) Wdst[tid + i * 256] = Wsrc[tid + i * 256];

  const int l  = tid & 63;
  const int w  = tid >> 6;
  const int lr = l & 31;
  const int lh = l >> 5;
  const int graph = blk * 2 + (w >> 1);        // 64 rows per graph -> 2 graphs/block
  float cbr[4], wp2r[4];
  #pragma unroll
  for (int t = 0; t < 4; ++t) {
    cbr[t]  = ws_cb[(size_t)graph * D + t * 32 + lr];
    wp2r[t] = Wp2[t * 32 + lr];
  }
  const float bp2v = bp2[0];

  __syncthreads();

  f32x16 acc[4] = {};
  const int arow = w * 32 + lr;
  #pragma unroll
  for (int s = 0; s < 8; ++s) {
    int k0 = s * 16 + lh * 8;
    bf16x8 af = *(const bf16x8*)((const char*)lds_a + arow * 256 +
                                 ((k0 * 2) ^ ((arow & 15) << 4)));
    #pragma unroll
    for (int t = 0; t < 4; ++t) {
      int col = t * 32 + lr;
      bf16x8 wf = *(const bf16x8*)((const char*)lds_w + col * 256 +
                                   ((k0 * 2) ^ ((col & 15) << 4)));
      acc[t] = __builtin_amdgcn_mfma_f32_32x32x16_bf16(af, wf, acc[t], 0, 0, 0);
    }
  }

  // epilogue: logit[row] = sum_col relu(S+cb)*wp2  (+bp2)
  float partial[16];
  #pragma unroll
  for (int r = 0; r < 16; ++r) partial[r] = 0.f;
  #pragma unroll
  for (int t = 0; t < 4; ++t)
    #pragma unroll
    for (int r = 0; r < 16; ++r) {
      float v = acc[t][r] + cbr[t];
      v = v > 0.f ? v : 0.f;
      partial[r] += v * wp2r[t];
    }
  #pragma unroll
  for (int m = 1; m < 32; m <<= 1)
    #pragma unroll
    for (int r = 0; r < 16; ++r) partial[r] += __shfl_xor(partial[r], m, 64);
  // C/D layout: col=lane&31, row=(r&3)+8*(r>>2)+4*(lane>>5)
  #pragma unroll
  for (int r = 0; r < 16; ++r) {
    if (lr == r) {
      int lrow = w * 32 + (r & 3) + 8 * (r >> 2) + 4 * lh;
      out[row0 + lrow] = partial[r] + bp2v;
    }
  }
}

// ---------------- kernel 3: edge-label MLP (f32 vector, 32 graphs/block) ----------------
__global__ __launch_bounds__(256) void k_label(
    const float* __restrict__ node, const float* __restrict__ glob,
    const float* __restrict__ Wl1, const float* __restrict__ bl1,
    const float* __restrict__ Wl2, const float* __restrict__ bl2,
    const float* __restrict__ Wl3, const float* __restrict__ bl3,
    const int* __restrict__ pgi, const int* __restrict__ pni,
    float* __restrict__ out)
{
  __shared__ float in_s[32][384];   // 48 KB (reused as h2 after layer 2)
  __shared__ float h1_s[32][128];   // 16 KB
  const int tid = threadIdx.x;
  const int b0 = blockIdx.x * 32;
  #pragma unroll
  for (int i = 0; i < 12; ++i) {
    int idx = tid + i * 256;        // float4 index, 3072 total
    int r = idx / 96, c4 = idx % 96;
    int b = b0 + r;
    int pg = pgi[b];
    int seg = c4 >> 5, o4 = c4 & 31;
    const float* src;
    if (seg == 0)      src = node + (size_t)((pg + 1) * NPG - 1) * D;
    else if (seg == 1) src = node + (size_t)pni[b] * D;
    else               src = glob + (size_t)pg * D;
    *(float4*)&in_s[r][c4 * 4] = ((const float4*)src)[o4];
  }
  __syncthreads();
  const int lane = tid & 31, grp = tid >> 5;   // 8 groups x 4 rows
  { // layer 1: [32x384]@[384x128] + relu
    float acc[4][4] = {};
    for (int k4 = 0; k4 < 96; ++k4) {
      int k = k4 * 4;
      float wv[4][4];
      #pragma unroll
      for (int kk = 0; kk < 4; ++kk) {
        const float* wp = Wl1 + (size_t)(k + kk) * D + lane;
        #pragma unroll
        for (int m = 0; m < 4; ++m) wv[kk][m] = wp[32 * m];
      }
      #pragma unroll
      for (int g = 0; g < 4; ++g) {
        float4 iv = *(const float4*)&in_s[grp * 4 + g][k];
        float ie[4] = {iv.x, iv.y, iv.z, iv.w};
        #pragma unroll
        for (int kk = 0; kk < 4; ++kk)
          #pragma unroll
          for (int m = 0; m < 4; ++m) acc[g][m] += ie[kk] * wv[kk][m];
      }
    }
    #pragma unroll
    for (int g = 0; g < 4; ++g)
      #pragma unroll
      for (int m = 0; m < 4; ++m) {
        int j = lane + 32 * m;
        float v = acc[g][m] + bl1[j];
        h1_s[grp * 4 + g][j] = v > 0.f ? v : 0.f;
      }
  }
  __syncthreads();
  float* h2_s = &in_s[0][0];        // 32*128 floats, aliases in_s (safe: in_s dead)
  { // layer 2: [32x128]@[128x128] + relu
    float acc[4][4] = {};
    for (int k4 = 0; k4 < 32; ++k4) {
      int k = k4 * 4;
      float wv[4][4];
      #pragma unroll
      for (int kk = 0; kk < 4; ++kk) {
        const float* wp = Wl2 + (size_t)(k + kk) * D + lane;
        #pragma unroll
        for (int m = 0; m < 4; ++m) wv[kk][m] = wp[32 * m];
      }
      #pragma unroll
      for (int g = 0; g < 4; ++g) {
        float4 iv = *(const float4*)&h1_s[grp * 4 + g][k];
        float ie[4] = {iv.x, iv.y, iv.z, iv.w};
        #pragma unroll
        for (int kk = 0; kk < 4; ++kk)
          #pragma unroll
          for (int m = 0; m < 4; ++m) acc[g][m] += ie[kk] * wv[kk][m];
      }
    }
    #pragma unroll
    for (int g = 0; g < 4; ++g)
      #pragma unroll
      for (int m = 0; m < 4; ++m) {
        int j = lane + 32 * m;
        float v = acc[g][m] + bl2[j];
        h2_s[(size_t)(grp * 4 + g) * 128 + j] = v > 0.f ? v : 0.f;
      }
  }
  __syncthreads();
  { // layer 3: [32x128]@[128x14]
    int j = tid & 15, g2 = tid >> 4;           // 16 groups x 2 rows
    if (j < NL) {
      float acc2[2] = {};
      for (int k4 = 0; k4 < 32; ++k4) {
        int k = k4 * 4;
        float wv[4];
        #pragma unroll
        for (int kk = 0; kk < 4; ++kk) wv[kk] = Wl3[(size_t)(k + kk) * NL + j];
        #pragma unroll
        for (int g = 0; g < 2; ++g) {
          float4 iv = *(const float4*)&h2_s[(size_t)(g2 * 2 + g) * 128 + k];
          acc2[g] += iv.x * wv[0] + iv.y * wv[1] + iv.z * wv[2] + iv.w * wv[3];
        }
      }
      #pragma unroll
      for (int g = 0; g < 2; ++g)
        out[(size_t)(b0 + g2 * 2 + g) * NL + j] = acc2[g] + bl3[j];
    }
  }
}

extern "C" void kernel_launch(void* const* d_in, const int* in_sizes, int n_in,
                              void* d_out, int out_size, void* d_ws, size_t ws_size,
                              hipStream_t stream) {
  const float* node = (const float*)d_in[0];
  const float* glob = (const float*)d_in[1];
  const float* Wp1  = (const float*)d_in[2];
  const float* bp1  = (const float*)d_in[3];
  const float* Wp2  = (const float*)d_in[4];
  const float* bp2  = (const float*)d_in[5];
  const float* Wl1  = (const float*)d_in[6];
  const float* bl1  = (const float*)d_in[7];
  const float* Wl2  = (const float*)d_in[8];
  const float* bl2  = (const float*)d_in[9];
  const float* Wl3  = (const float*)d_in[10];
  const float* bl3  = (const float*)d_in[11];
  const int* pgi = (const int*)d_in[12];
  const int* pni = (const int*)d_in[13];
  float* out = (float*)d_out;

  float* ws_cb = (float*)d_ws;                                    // 8192*128 f32 = 4 MB
  unsigned short* ws_wmid =
      (unsigned short*)((char*)d_ws + (size_t)BG * D * sizeof(float)); // 32 KB

  hipLaunchKernelGGL(k_prep, dim3(257), dim3(256), 0, stream,
                     node, glob, Wp1, bp1, ws_cb, ws_wmid);
  hipLaunchKernelGGL(k_partner, dim3(4096), dim3(256), 0, stream,
                     node, ws_wmid, ws_cb, Wp2, bp2, out);
  hipLaunchKernelGGL(k_label, dim3(256), dim3(256), 0, stream,
                     node, glob, Wl1, bl1, Wl2, bl2, Wl3, bl3, pgi, pni,
                     out + (size_t)NNODES);
}

// Round 2
// 479.276 us; speedup vs baseline: 1.0391x; 1.0391x over previous
//
#include <hip/hip_runtime.h>

#define D 128
#define BG 8192
#define NPG 64
#define NNODES (BG * NPG)
#define NL 14

#define LBLK 1024          // label blocks (8 graphs each)
#define PBLK 4096          // partner blocks (128 rows each)

typedef __attribute__((ext_vector_type(8))) __bf16 bf16x8;
typedef __attribute__((ext_vector_type(16))) float f32x16;

__device__ __forceinline__ unsigned short f2bf(float f) {
  unsigned int u = __float_as_uint(f);
  u += 0x7fffu + ((u >> 16) & 1u);
  return (unsigned short)(u >> 16);
}

// ---------------- kernel 1: cbias (per-graph partner bias) + W fragment prep ----------------
// blocks 0..255: cbias for 32 graphs each.
// block 256: repack Wp1[128:256] (node-block) to bf16 in per-lane MFMA fragment
// order: u16 index e = ((s*4+t)*64 + l)*8 + i  with  k=s*16+(l>>5)*8+i, col=t*32+(l&31).
__global__ __launch_bounds__(256) void k_prep(
    const float* __restrict__ node, const float* __restrict__ glob,
    const float* __restrict__ Wp1, const float* __restrict__ bp1,
    float* __restrict__ ws_cb, unsigned short* __restrict__ ws_wmid)
{
  const int tid = threadIdx.x;
  const int blk = blockIdx.x;
  if (blk == 256) {
    #pragma unroll
    for (int ii = 0; ii < 64; ++ii) {
      int f = tid + ii * 256;            // 16384 elements
      int k = f >> 7, col = f & 127;
      int s = k >> 4, lh = (k >> 3) & 1, i8 = k & 7;
      int t = col >> 5, lr = col & 31;
      int e = ((s * 4 + t) * 64 + lh * 32 + lr) * 8 + i8;
      ws_wmid[e] = f2bf(Wp1[(size_t)(128 + k) * D + col]);
    }
    return;
  }
  __shared__ float in_s[32][256];        // [graph][cur(128) | glob(128)]
  const int g0 = blk * 32;
  #pragma unroll
  for (int i = 0; i < 8; ++i) {
    int idx = tid + i * 256;             // float4 index, 2048 total
    int r = idx >> 6, c4 = idx & 63;
    int g = g0 + r;
    float4 v;
    if (c4 < 32) v = ((const float4*)(node + (size_t)((g + 1) * NPG - 1) * D))[c4];
    else         v = ((const float4*)(glob + (size_t)g * D))[c4 - 32];
    *(float4*)&in_s[r][c4 * 4] = v;
  }
  __syncthreads();
  const int lane = tid & 31, grp = tid >> 5;   // 8 half-waves x 4 graphs
  float acc[4][4] = {};
  for (int k4 = 0; k4 < 64; ++k4) {
    int k = k4 * 4;
    float4 wv[4];
    #pragma unroll
    for (int kk = 0; kk < 4; ++kk) {
      int krow = k + kk;
      int wr = krow < 128 ? krow : krow + 128;   // skip node-block of Wp1
      wv[kk] = *(const float4*)&Wp1[(size_t)wr * D + lane * 4];
    }
    #pragma unroll
    for (int g = 0; g < 4; ++g) {
      float4 iv = *(const float4*)&in_s[grp * 4 + g][k];
      float ie[4] = {iv.x, iv.y, iv.z, iv.w};
      #pragma unroll
      for (int kk = 0; kk < 4; ++kk) {
        acc[g][0] += ie[kk] * wv[kk].x;
        acc[g][1] += ie[kk] * wv[kk].y;
        acc[g][2] += ie[kk] * wv[kk].z;
        acc[g][3] += ie[kk] * wv[kk].w;
      }
    }
  }
  float4 b4 = *(const float4*)&bp1[lane * 4];
  float be[4] = {b4.x, b4.y, b4.z, b4.w};
  #pragma unroll
  for (int g = 0; g < 4; ++g) {
    float4 o;
    o.x = acc[g][0] + be[0]; o.y = acc[g][1] + be[1];
    o.z = acc[g][2] + be[2]; o.w = acc[g][3] + be[3];
    *(float4*)&ws_cb[(size_t)(g0 + grp * 4 + g) * D + lane * 4] = o;
  }
}

// ---------------- kernel 2: fused main ----------------
// blocks [0, LBLK): edge-label MLP, 8 graphs each.
// blocks [LBLK, LBLK+PBLK): partner logits, 128 node rows each (MFMA, A from
// global directly to regs, W from LDS in fragment order).
__global__ __launch_bounds__(256, 4) void k_main(
    const float* __restrict__ node, const float* __restrict__ glob,
    const unsigned short* __restrict__ wmid,
    const float* __restrict__ ws_cb,
    const float* __restrict__ Wp2, const float* __restrict__ bp2,
    const float* __restrict__ Wl1, const float* __restrict__ bl1,
    const float* __restrict__ Wl2, const float* __restrict__ bl2,
    const float* __restrict__ Wl3, const float* __restrict__ bl3,
    const int* __restrict__ pgi, const int* __restrict__ pni,
    float* __restrict__ out)
{
  __shared__ float smem[8192];           // 32 KB union
  const int tid = threadIdx.x;
  const int blk = blockIdx.x;

  if (blk >= LBLK) {
    // ---------------- partner path ----------------
    unsigned short* wlds = (unsigned short*)smem;
    const int pblk = blk - LBLK;
    const size_t row0 = (size_t)pblk * 128;

    // stage W: 32 KB flat copy (already fragment-ordered in ws)
    {
      const uint4* src = (const uint4*)wmid;
      uint4* dst = (uint4*)smem;
      #pragma unroll
      for (int i = 0; i < 8; ++i) dst[tid + i * 256] = src[tid + i * 256];
    }

    const int l  = tid & 63;
    const int w  = tid >> 6;
    const int lr = l & 31;
    const int lh = l >> 5;
    const int graph = pblk * 2 + (w >> 1);       // 64 rows/graph -> 2 graphs/block
    float cbr[4], wp2r[4];
    #pragma unroll
    for (int t = 0; t < 4; ++t) {
      cbr[t]  = ws_cb[(size_t)graph * D + t * 32 + lr];
      wp2r[t] = Wp2[t * 32 + lr];
    }
    const float bp2v = bp2[0];

    __syncthreads();

    f32x16 acc[4] = {};
    const float* Ap = node + (row0 + w * 32 + lr) * D + lh * 8;
    #pragma unroll 2
    for (int s = 0; s < 8; ++s) {
      float4 a0 = *(const float4*)(Ap + s * 16);
      float4 a1 = *(const float4*)(Ap + s * 16 + 4);
      bf16x8 af;
      af[0] = (__bf16)a0.x; af[1] = (__bf16)a0.y;
      af[2] = (__bf16)a0.z; af[3] = (__bf16)a0.w;
      af[4] = (__bf16)a1.x; af[5] = (__bf16)a1.y;
      af[6] = (__bf16)a1.z; af[7] = (__bf16)a1.w;
      #pragma unroll
      for (int t = 0; t < 4; ++t) {
        bf16x8 wf = *(const bf16x8*)&wlds[(size_t)((s * 4 + t) * 64 + l) * 8];
        acc[t] = __builtin_amdgcn_mfma_f32_32x32x16_bf16(af, wf, acc[t], 0, 0, 0);
      }
    }

    // epilogue: logit[row] = sum_col relu(S+cb)*wp2 (+bp2)
    float partial[16];
    #pragma unroll
    for (int r = 0; r < 16; ++r) partial[r] = 0.f;
    #pragma unroll
    for (int t = 0; t < 4; ++t)
      #pragma unroll
      for (int r = 0; r < 16; ++r) {
        float v = acc[t][r] + cbr[t];
        v = v > 0.f ? v : 0.f;
        partial[r] += v * wp2r[t];
      }
    #pragma unroll
    for (int m = 1; m < 32; m <<= 1)
      #pragma unroll
      for (int r = 0; r < 16; ++r) partial[r] += __shfl_xor(partial[r], m, 64);
    // C/D layout: col=lane&31, row=(r&3)+8*(r>>2)+4*(lane>>5)
    #pragma unroll
    for (int r = 0; r < 16; ++r) {
      if (lr == r) {
        int lrow = w * 32 + (r & 3) + 8 * (r >> 2) + 4 * lh;
        out[row0 + lrow] = partial[r] + bp2v;
      }
    }
    return;
  }

  // ---------------- label path: 8 graphs/block ----------------
  float (*in_s)[384] = (float (*)[384])smem;            // 12 KB
  float (*h1_s)[128] = (float (*)[128])(smem + 8 * 384); // 4 KB
  const int b0 = blk * 8;
  #pragma unroll
  for (int i = 0; i < 3; ++i) {
    int idx = tid + i * 256;             // float4 index, 768 total
    int r = idx / 96, c4 = idx % 96;
    int b = b0 + r;
    int pg = pgi[b];
    int seg = c4 >> 5, o4 = c4 & 31;
    const float* src;
    if (seg == 0)      src = node + (size_t)((pg + 1) * NPG - 1) * D;
    else if (seg == 1) src = node + (size_t)pni[b] * D;
    else               src = glob + (size_t)pg * D;
    *(float4*)&in_s[r][c4 * 4] = ((const float4*)src)[o4];
  }
  __syncthreads();
  const int lane = tid & 31, grp = tid >> 5;   // 8 half-waves x 1 graph
  { // layer 1: [8x384]@[384x128] + relu
    float acc[4] = {};
    for (int k4 = 0; k4 < 96; ++k4) {
      int k = k4 * 4;
      float4 wv[4];
      #pragma unroll
      for (int kk = 0; kk < 4; ++kk)
        wv[kk] = *(const float4*)&Wl1[(size_t)(k + kk) * D + lane * 4];
      float4 iv = *(const float4*)&in_s[grp][k];
      float ie[4] = {iv.x, iv.y, iv.z, iv.w};
      #pragma unroll
      for (int kk = 0; kk < 4; ++kk) {
        acc[0] += ie[kk] * wv[kk].x; acc[1] += ie[kk] * wv[kk].y;
        acc[2] += ie[kk] * wv[kk].z; acc[3] += ie[kk] * wv[kk].w;
      }
    }
    float4 b4 = *(const float4*)&bl1[lane * 4];
    float4 o;
    o.x = fmaxf(acc[0] + b4.x, 0.f); o.y = fmaxf(acc[1] + b4.y, 0.f);
    o.z = fmaxf(acc[2] + b4.z, 0.f); o.w = fmaxf(acc[3] + b4.w, 0.f);
    *(float4*)&h1_s[grp][lane * 4] = o;
  }
  __syncthreads();
  float* h2_s = &in_s[0][0];             // 8*128 floats, aliases in_s (in_s dead)
  { // layer 2: [8x128]@[128x128] + relu
    float acc[4] = {};
    for (int k4 = 0; k4 < 32; ++k4) {
      int k = k4 * 4;
      float4 wv[4];
      #pragma unroll
      for (int kk = 0; kk < 4; ++kk)
        wv[kk] = *(const float4*)&Wl2[(size_t)(k + kk) * D + lane * 4];
      float4 iv = *(const float4*)&h1_s[grp][k];
      float ie[4] = {iv.x, iv.y, iv.z, iv.w};
      #pragma unroll
      for (int kk = 0; kk < 4; ++kk) {
        acc[0] += ie[kk] * wv[kk].x; acc[1] += ie[kk] * wv[kk].y;
        acc[2] += ie[kk] * wv[kk].z; acc[3] += ie[kk] * wv[kk].w;
      }
    }
    float4 b4 = *(const float4*)&bl2[lane * 4];
    float4 o;
    o.x = fmaxf(acc[0] + b4.x, 0.f); o.y = fmaxf(acc[1] + b4.y, 0.f);
    o.z = fmaxf(acc[2] + b4.z, 0.f); o.w = fmaxf(acc[3] + b4.w, 0.f);
    __syncthreads();                      // in_s reads done before overwrite
    *(float4*)&h2_s[(size_t)grp * 128 + lane * 4] = o;
  }
  __syncthreads();
  { // layer 3: [8x128]@[128x14]
    int j = tid & 15, g2 = tid >> 4;     // 16 groups x 1 graph, 8 valid
    if (g2 < 8 && j < NL) {
      float acc2 = 0.f;
      for (int k4 = 0; k4 < 32; ++k4) {
        int k = k4 * 4;
        float wv[4];
        #pragma unroll
        for (int kk = 0; kk < 4; ++kk) wv[kk] = Wl3[(size_t)(k + kk) * NL + j];
        float4 iv = *(const float4*)&h2_s[(size_t)g2 * 128 + k];
        acc2 += iv.x * wv[0] + iv.y * wv[1] + iv.z * wv[2] + iv.w * wv[3];
      }
      out[(size_t)NNODES + (size_t)(b0 + g2) * NL + j] = acc2 + bl3[j];
    }
  }
}

extern "C" void kernel_launch(void* const* d_in, const int* in_sizes, int n_in,
                              void* d_out, int out_size, void* d_ws, size_t ws_size,
                              hipStream_t stream) {
  const float* node = (const float*)d_in[0];
  const float* glob = (const float*)d_in[1];
  const float* Wp1  = (const float*)d_in[2];
  const float* bp1  = (const float*)d_in[3];
  const float* Wp2  = (const float*)d_in[4];
  const float* bp2  = (const float*)d_in[5];
  const float* Wl1  = (const float*)d_in[6];
  const float* bl1  = (const float*)d_in[7];
  const float* Wl2  = (const float*)d_in[8];
  const float* bl2  = (const float*)d_in[9];
  const float* Wl3  = (const float*)d_in[10];
  const float* bl3  = (const float*)d_in[11];
  const int* pgi = (const int*)d_in[12];
  const int* pni = (const int*)d_in[13];
  float* out = (float*)d_out;

  float* ws_cb = (float*)d_ws;                                        // 4 MB
  unsigned short* ws_wmid =
      (unsigned short*)((char*)d_ws + (size_t)BG * D * sizeof(float)); // 32 KB

  hipLaunchKernelGGL(k_prep, dim3(257), dim3(256), 0, stream,
                     node, glob, Wp1, bp1, ws_cb, ws_wmid);
  hipLaunchKernelGGL(k_main, dim3(LBLK + PBLK), dim3(256), 0, stream,
                     node, glob, ws_wmid, ws_cb, Wp2, bp2,
                     Wl1, bl1, Wl2, bl2, Wl3, bl3, pgi, pni, out);
}